// Round 1
// baseline (891.043 us; speedup 1.0000x reference)
//
#include <hip/hip_runtime.h>

#define BATCH 4
#define SEQ   2048
#define DIM   2048
#define NH    16
#define HD    128

typedef __bf16 bf16x8 __attribute__((ext_vector_type(8)));
typedef float  f32x4  __attribute__((ext_vector_type(4)));

__device__ __forceinline__ unsigned short f2bf(float f) {
  unsigned int u = __builtin_bit_cast(unsigned int, f);
  u += 0x7fffu + ((u >> 16) & 1u);          // RNE
  return (unsigned short)(u >> 16);
}
__device__ __forceinline__ float bf2f(unsigned short h) {
  unsigned int u = ((unsigned int)h) << 16;
  return __builtin_bit_cast(float, u);
}

// async global->LDS, 16B per lane; LDS dest must be wave-uniform-base + lane*16
__device__ __forceinline__ void async16(void* lds, const void* g) {
  __builtin_amdgcn_global_load_lds(
      (const __attribute__((address_space(1))) unsigned int*)g,
      (__attribute__((address_space(3))) unsigned int*)lds, 16, 0, 0);
}

// ---------------------------------------------------------------- casts
__global__ __launch_bounds__(256) void cast_bf16_kernel(
    const float* __restrict__ src, unsigned short* __restrict__ dst, int n4) {
  int i = blockIdx.x * 256 + threadIdx.x;
  if (i >= n4) return;
  float4 v = ((const float4*)src)[i];
  ushort4 o;
  o.x = f2bf(v.x); o.y = f2bf(v.y); o.z = f2bf(v.z); o.w = f2bf(v.w);
  ((ushort4*)dst)[i] = o;
}

// ---------------------------------------------------------------- RoPE (in-place, layout (B*H, S, HD))
__global__ __launch_bounds__(256) void rope_kernel(unsigned short* __restrict__ T) {
  int idx = blockIdx.x * 256 + threadIdx.x;   // BATCH*NH*SEQ*64 threads
  int i  = idx & 63;
  int s  = (idx >> 6) & (SEQ - 1);
  int bh = idx >> 17;
  size_t base = ((size_t)bh * SEQ + s) * HD;
  // inv_freq[i] = 10000^(-i/64) = 2^(-i*log2(10000)/64)
  float ang = (float)s * exp2f(-(float)i * 0.20762050593046932f);
  float c = cosf(ang), sn = sinf(ang);
  float t1 = bf2f(T[base + i]);
  float t2 = bf2f(T[base + i + 64]);
  T[base + i]      = f2bf(t1 * c - t2 * sn);
  T[base + i + 64] = f2bf(t2 * c + t1 * sn);
}

// ---------------------------------------------------------------- V (B*H,S,HD) -> Vt (B*H,HD,S)
__global__ __launch_bounds__(256) void transpose_v(
    const unsigned short* __restrict__ V, unsigned short* __restrict__ Vt) {
  __shared__ unsigned short tile[64 * 72];   // 64 s-rows x 64 d-cols, pad 8
  int s0 = blockIdx.x * 64;
  int d0 = blockIdx.y * 64;
  int bh = blockIdx.z;
  int tid = threadIdx.x;
#pragma unroll
  for (int i = 0; i < 2; ++i) {
    int idx = i * 256 + tid;
    int r = idx >> 3, c = idx & 7;
    *(uint4*)&tile[r * 72 + c * 8] =
        *(const uint4*)(V + ((size_t)bh * SEQ + s0 + r) * HD + d0 + c * 8);
  }
  __syncthreads();
#pragma unroll
  for (int i = 0; i < 2; ++i) {
    int idx = i * 256 + tid;
    int rt = idx >> 3, c = idx & 7;          // rt = d-local, c = s-octet
    unsigned short o[8];
#pragma unroll
    for (int j = 0; j < 8; ++j) o[j] = tile[(c * 8 + j) * 72 + rt];
    *(uint4*)(Vt + ((size_t)bh * HD + d0 + rt) * SEQ + s0 + c * 8) = *(uint4*)o;
  }
}

// ---------------------------------------------------------------- GEMM: C[M,N] = A[M,K] * Bw[N,K]^T
// 128x128 tile, BK=32, 256 threads (4 waves 2x2, each 64x64 via 4x4 mfma_16x16x32_bf16)
// MODE 0: write bf16 scatter to (B,H,S,HD).  MODE 1: write fp32 M*N + bias.
template <int MODE>
__global__ __launch_bounds__(256) void gemm_bt(
    const unsigned short* __restrict__ A,
    const unsigned short* __restrict__ Bw,
    unsigned short* __restrict__ outb,
    float* __restrict__ outf,
    const float* __restrict__ bias,
    int K) {
  __shared__ unsigned short As[128 * 32];
  __shared__ unsigned short Bs[128 * 32];
  const int tid = threadIdx.x;
  const int lane = tid & 63, wv = tid >> 6;
  const int q15 = lane & 15, quad = lane >> 4;
  const int wm = wv >> 1, wn = wv & 1;
  const int n0 = blockIdx.x * 128, m0 = blockIdx.y * 128;

  f32x4 acc[4][4] = {};

  for (int kt = 0; kt < K; kt += 32) {
    __syncthreads();
    // stage A,B tiles: chunk (r,c) stored at slot r*4 + ((c + (r>>1))&3)  [xor-ish swizzle]
#pragma unroll
    for (int i = 0; i < 2; ++i) {
      int l = i * 256 + tid;
      int r = l >> 2, s = l & 3;
      int c = (s - (r >> 1)) & 3;
      async16(&As[l * 8], A + (size_t)(m0 + r) * K + kt + c * 8);
    }
#pragma unroll
    for (int i = 0; i < 2; ++i) {
      int l = i * 256 + tid;
      int r = l >> 2, s = l & 3;
      int c = (s - (r >> 1)) & 3;
      async16(&Bs[l * 8], Bw + (size_t)(n0 + r) * K + kt + c * 8);
    }
    __syncthreads();

    bf16x8 af[4], bf[4];
#pragma unroll
    for (int mf = 0; mf < 4; ++mf) {
      int r = wm * 64 + mf * 16 + q15;
      int sl = r * 4 + ((quad + (r >> 1)) & 3);
      af[mf] = *(const bf16x8*)&As[sl * 8];
    }
#pragma unroll
    for (int nf = 0; nf < 4; ++nf) {
      int r = wn * 64 + nf * 16 + q15;
      int sl = r * 4 + ((quad + (r >> 1)) & 3);
      bf[nf] = *(const bf16x8*)&Bs[sl * 8];
    }
#pragma unroll
    for (int mf = 0; mf < 4; ++mf)
#pragma unroll
      for (int nf = 0; nf < 4; ++nf)
        acc[mf][nf] = __builtin_amdgcn_mfma_f32_16x16x32_bf16(af[mf], bf[nf], acc[mf][nf], 0, 0, 0);
  }

  if constexpr (MODE == 0) {
    // (m,n) -> (B,H,S,HD); n-tile (128) == one head exactly
    int b = m0 >> 11;          // m0 / SEQ
    int sbase = m0 & (SEQ - 1);
    int h = n0 >> 7;
#pragma unroll
    for (int mf = 0; mf < 4; ++mf)
#pragma unroll
      for (int nf = 0; nf < 4; ++nf) {
        int col = wn * 64 + nf * 16 + q15;   // hd
#pragma unroll
        for (int r = 0; r < 4; ++r) {
          int row = wm * 64 + mf * 16 + quad * 4 + r;
          outb[((size_t)(b * NH + h) * SEQ + sbase + row) * HD + col] = f2bf(acc[mf][nf][r]);
        }
      }
  } else {
#pragma unroll
    for (int mf = 0; mf < 4; ++mf)
#pragma unroll
      for (int nf = 0; nf < 4; ++nf) {
        int col = n0 + wn * 64 + nf * 16 + q15;
        float bv = bias[col];
#pragma unroll
        for (int r = 0; r < 4; ++r) {
          int row = m0 + wm * 64 + mf * 16 + quad * 4 + r;
          outf[(size_t)row * DIM + col] = acc[mf][nf][r] + bv;
        }
      }
  }
}

// ---------------------------------------------------------------- flash attention
// block = (b,h,q-tile of 128); 4 waves, each owns 32 q rows.
// KV tiles of 64; K LDS (64x128) and Vt LDS (128x64) xor-swizzled; P via wave-private LDS.
__global__ __launch_bounds__(256) void attn_kernel(
    const unsigned short* __restrict__ Q,    // (B*H, S, HD) rope'd
    const unsigned short* __restrict__ Kg,   // (B*H, S, HD) rope'd
    const unsigned short* __restrict__ Vt,   // (B*H, HD, S)
    unsigned short* __restrict__ O) {        // (B, S, H, HD) bf16
  __shared__ unsigned short Ks[64 * 128];
  __shared__ unsigned short Vs[128 * 64];
  __shared__ unsigned short Ps[4 * 32 * 72];
  const int tid = threadIdx.x;
  const int lane = tid & 63, wv = tid >> 6;
  const int q15 = lane & 15, quad = lane >> 4;
  const int bh = blockIdx.x & 63;
  const int qt = 15 - (blockIdx.x >> 6);     // heavy q-tiles dispatch first
  const int q0 = qt * 128;
  const int b = bh >> 4, h = bh & 15;
  const float CS = 0.12751744f;              // (1/sqrt(128)) * log2(e)

  // Q A-fragments held in registers for the whole block
  bf16x8 qf[2][4];
#pragma unroll
  for (int mf = 0; mf < 2; ++mf) {
    int qrow = q0 + wv * 32 + mf * 16 + q15;
    const unsigned short* qp = Q + ((size_t)bh * SEQ + qrow) * HD + quad * 8;
#pragma unroll
    for (int ks = 0; ks < 4; ++ks) qf[mf][ks] = *(const bf16x8*)(qp + ks * 32);
  }

  f32x4 oacc[2][8] = {};
  float m_i[2][4], l_i[2][4];
#pragma unroll
  for (int mf = 0; mf < 2; ++mf)
#pragma unroll
    for (int r = 0; r < 4; ++r) { m_i[mf][r] = -1e30f; l_i[mf][r] = 0.f; }

  unsigned short* Pw = Ps + wv * (32 * 72);
  const int jmax = 2 * qt + 2;

  for (int j = 0; j < jmax; ++j) {
    const int kv0 = j * 64;
    __syncthreads();   // previous tile's LDS reads done
    // K tile: chunk (r kv-row<64, c d-octet<16) at slot r*16 + (c ^ (r&15))
#pragma unroll
    for (int i = 0; i < 4; ++i) {
      int l = i * 256 + tid;
      int r = l >> 4, c = (l & 15) ^ (r & 15);
      async16(&Ks[l * 8], Kg + ((size_t)bh * SEQ + kv0 + r) * HD + c * 8);
    }
    // Vt tile: chunk (r d-row<128, c kv-octet<8) at slot r*8 + (c ^ (r&7))
#pragma unroll
    for (int i = 0; i < 4; ++i) {
      int l = i * 256 + tid;
      int r = l >> 3, c = (l & 7) ^ (r & 7);
      async16(&Vs[l * 8], Vt + ((size_t)bh * HD + r) * SEQ + kv0 + c * 8);
    }
    __syncthreads();   // drains global_load_lds (vmcnt(0) before barrier)

    // S = Q K^T  (raw, unscaled)
    f32x4 sa[2][4] = {};
#pragma unroll
    for (int ks = 0; ks < 4; ++ks) {
      bf16x8 kf[4];
#pragma unroll
      for (int nf = 0; nf < 4; ++nf) {
        int r = nf * 16 + q15;
        int c = ks * 4 + quad;
        int sl = r * 16 + (c ^ (r & 15));
        kf[nf] = *(const bf16x8*)&Ks[sl * 8];
      }
#pragma unroll
      for (int mf = 0; mf < 2; ++mf)
#pragma unroll
        for (int nf = 0; nf < 4; ++nf)
          sa[mf][nf] = __builtin_amdgcn_mfma_f32_16x16x32_bf16(qf[mf][ks], kf[nf], sa[mf][nf], 0, 0, 0);
    }

    if (j >= 2 * qt) {   // causal mask needed only on last two tiles
#pragma unroll
      for (int mf = 0; mf < 2; ++mf)
#pragma unroll
        for (int nf = 0; nf < 4; ++nf)
#pragma unroll
          for (int r = 0; r < 4; ++r) {
            int kv = kv0 + nf * 16 + q15;
            int qq = q0 + wv * 32 + mf * 16 + quad * 4 + r;
            if (kv > qq) sa[mf][nf][r] = -1e30f;
          }
    }

    // online softmax (rows live within one 16-lane group)
#pragma unroll
    for (int mf = 0; mf < 2; ++mf) {
#pragma unroll
      for (int r = 0; r < 4; ++r) {
        float mx = fmaxf(fmaxf(sa[mf][0][r], sa[mf][1][r]), fmaxf(sa[mf][2][r], sa[mf][3][r]));
        mx = fmaxf(mx, __shfl_xor(mx, 1));
        mx = fmaxf(mx, __shfl_xor(mx, 2));
        mx = fmaxf(mx, __shfl_xor(mx, 4));
        mx = fmaxf(mx, __shfl_xor(mx, 8));
        float mnew = fmaxf(m_i[mf][r], mx);
        float alpha = exp2f((m_i[mf][r] - mnew) * CS);
        m_i[mf][r] = mnew;
        float mc = mnew * CS;
        float rs = 0.f;
        float p[4];
#pragma unroll
        for (int nf = 0; nf < 4; ++nf) {
          p[nf] = exp2f(sa[mf][nf][r] * CS - mc);
          rs += p[nf];
        }
        rs += __shfl_xor(rs, 1);
        rs += __shfl_xor(rs, 2);
        rs += __shfl_xor(rs, 4);
        rs += __shfl_xor(rs, 8);
        l_i[mf][r] = l_i[mf][r] * alpha + rs;
#pragma unroll
        for (int nf8 = 0; nf8 < 8; ++nf8) oacc[mf][nf8][r] *= alpha;
        int prow = mf * 16 + quad * 4 + r;
#pragma unroll
        for (int nf = 0; nf < 4; ++nf)
          Pw[prow * 72 + nf * 16 + q15] = f2bf(p[nf]);
      }
    }

    // O += P @ V   (wave-private P, no barrier needed)
#pragma unroll
    for (int ks = 0; ks < 2; ++ks) {
      bf16x8 pf[2];
#pragma unroll
      for (int mf = 0; mf < 2; ++mf)
        pf[mf] = *(const bf16x8*)&Pw[(mf * 16 + q15) * 72 + ks * 32 + quad * 8];
#pragma unroll
      for (int nf = 0; nf < 8; ++nf) {
        int r = nf * 16 + q15;
        int c = ks * 4 + quad;
        int sl = r * 8 + (c ^ (r & 7));
        bf16x8 vf = *(const bf16x8*)&Vs[sl * 8];
#pragma unroll
        for (int mf = 0; mf < 2; ++mf)
          oacc[mf][nf] = __builtin_amdgcn_mfma_f32_16x16x32_bf16(pf[mf], vf, oacc[mf][nf], 0, 0, 0);
      }
    }
  }

  // epilogue: O /= l, write (B,S,H,HD) bf16
#pragma unroll
  for (int mf = 0; mf < 2; ++mf)
#pragma unroll
    for (int r = 0; r < 4; ++r) {
      float inv = 1.0f / l_i[mf][r];
      int qq = q0 + wv * 32 + mf * 16 + quad * 4 + r;
      size_t base = (((size_t)b * SEQ + qq) * NH + h) * HD;
#pragma unroll
      for (int nf = 0; nf < 8; ++nf)
        O[base + nf * 16 + q15] = f2bf(oacc[mf][nf][r] * inv);
    }
}

// ---------------------------------------------------------------- launch
extern "C" void kernel_launch(void* const* d_in, const int* in_sizes, int n_in,
                              void* d_out, int out_size, void* d_ws, size_t ws_size,
                              hipStream_t stream) {
  (void)in_sizes; (void)n_in; (void)out_size; (void)ws_size;
  const float* x  = (const float*)d_in[0];
  const float* Wq = (const float*)d_in[1];
  const float* Wk = (const float*)d_in[2];
  const float* Wv = (const float*)d_in[3];
  const float* Wo = (const float*)d_in[4];
  const float* bo = (const float*)d_in[5];
  float* out = (float*)d_out;

  const size_t XE = (size_t)BATCH * SEQ * DIM;   // 16.7M elems
  const size_t WE = (size_t)DIM * DIM;           // 4.2M elems

  char* p = (char*)d_ws;
  unsigned short* xb  = (unsigned short*)p; p += XE * 2;
  unsigned short* Wqb = (unsigned short*)p; p += WE * 2;
  unsigned short* Wkb = (unsigned short*)p; p += WE * 2;
  unsigned short* Wvb = (unsigned short*)p; p += WE * 2;
  unsigned short* Wob = (unsigned short*)p; p += WE * 2;
  unsigned short* Qg  = (unsigned short*)p; p += XE * 2;
  unsigned short* Kb  = (unsigned short*)p; p += XE * 2;
  unsigned short* Vb  = (unsigned short*)p; p += XE * 2;   // reused as attn output
  unsigned short* Vtb = (unsigned short*)p; p += XE * 2;
  unsigned short* attn = Vb;

  cast_bf16_kernel<<<(int)(XE / 4 / 256), 256, 0, stream>>>(x,  xb,  (int)(XE / 4));
  cast_bf16_kernel<<<(int)(WE / 4 / 256), 256, 0, stream>>>(Wq, Wqb, (int)(WE / 4));
  cast_bf16_kernel<<<(int)(WE / 4 / 256), 256, 0, stream>>>(Wk, Wkb, (int)(WE / 4));
  cast_bf16_kernel<<<(int)(WE / 4 / 256), 256, 0, stream>>>(Wv, Wvb, (int)(WE / 4));
  cast_bf16_kernel<<<(int)(WE / 4 / 256), 256, 0, stream>>>(Wo, Wob, (int)(WE / 4));

  dim3 gg(DIM / 128, (BATCH * SEQ) / 128);
  gemm_bt<0><<<gg, 256, 0, stream>>>(xb, Wqb, Qg, nullptr, nullptr, DIM);
  gemm_bt<0><<<gg, 256, 0, stream>>>(xb, Wkb, Kb, nullptr, nullptr, DIM);
  gemm_bt<0><<<gg, 256, 0, stream>>>(xb, Wvb, Vb, nullptr, nullptr, DIM);

  int ropeN = BATCH * NH * SEQ * 64;
  rope_kernel<<<ropeN / 256, 256, 0, stream>>>(Qg);
  rope_kernel<<<ropeN / 256, 256, 0, stream>>>(Kb);

  transpose_v<<<dim3(SEQ / 64, HD / 64, BATCH * NH), 256, 0, stream>>>(Vb, Vtb);

  attn_kernel<<<dim3(16 * 64), 256, 0, stream>>>(Qg, Kb, Vtb, attn);

  gemm_bt<1><<<gg, 256, 0, stream>>>(attn, Wob, nullptr, out, bo, DIM);
}